// Round 3
// baseline (220.638 us; speedup 1.0000x reference)
//
#include <hip/hip_runtime.h>

typedef unsigned short u16;
typedef __attribute__((ext_vector_type(8))) short bf16x8;
typedef __attribute__((ext_vector_type(4))) float f32x4;

// round-to-nearest (ties away): 2 VALU ops
__device__ __forceinline__ u16 f2bf(float f) {
    return (u16)((__float_as_uint(f) + 0x8000u) >> 16);
}

#define N_NODES 2048
#define D_EMB 64
#define P_DIM 32
#define NS_STOPS 512
#define IN_LEN 4131   // 32 + 2048 + 2048 + 3
#define NKT 65        // K-tiles of 64 (2048 es + 2048 dist + 32 pref + 32 pad)

// 16B-chunk XOR swizzle within a tile row (8 chunks of 8 shorts)
#define SWZ(row, c) ((((row) * 8) + ((c) ^ ((row) & 7))) * 8)

__device__ __forceinline__ void gload16(const u16* g, u16* l) {
    __builtin_amdgcn_global_load_lds((const __attribute__((address_space(1))) void*)g,
                                     (__attribute__((address_space(3))) void*)l, 16, 0, 0);
}

// ---------------- fused: stops bitmap + cosine graph + mean agg + pref + a,b (self-contained) ----------------
__global__ __launch_bounds__(256) void k_aggpref(const float* __restrict__ emb, const int* __restrict__ stops,
                                                 const float* __restrict__ lin_l_w, const float* __restrict__ lin_l_b,
                                                 const float* __restrict__ lin_r_w, const float* __restrict__ edge_w,
                                                 float* __restrict__ pref, float* __restrict__ av, float* __restrict__ bv) {
    int i = blockIdx.x, t = threadIdx.x;
    __shared__ int bm[64];          // 2048-bit stop bitmap
    __shared__ int kl[NS_STOPS];
    __shared__ int cnt, degL;
    __shared__ float xi[D_EMB];     // raw emb row i
    __shared__ float aggL[D_EMB];
    __shared__ float niS;
    if (t < 64) bm[t] = 0;
    if (t == 0) { cnt = 0; degL = 0; }
    if (t < D_EMB) { xi[t] = emb[i * D_EMB + t]; aggL[t] = 0.f; }
    __syncthreads();
    {   // scatter stops into bitmap
        int s0 = stops[t], s1 = stops[t + 256];
        atomicOr(&bm[s0 >> 5], 1 << (s0 & 31));
        atomicOr(&bm[s1 >> 5], 1 << (s1 & 31));
    }
    __syncthreads();
    {   // compact set nodes into kl
        int w = bm[t >> 2];          // thread t covers bits (t&3)*8 .. +7 of word t>>2
        int base = (t >> 2) * 32 + (t & 3) * 8;
        #pragma unroll
        for (int e = 0; e < 8; ++e)
            if ((w >> ((t & 3) * 8 + e)) & 1) { int p = atomicAdd(&cnt, 1); kl[p] = base + e; }
    }
    // norm of row i (wave 0)
    if (t < 64) {
        float s = xi[t] * xi[t];
        #pragma unroll
        for (int off = 32; off; off >>= 1) s += __shfl_xor(s, off, 64);
        if (t == 0) niS = fmaxf(sqrtf(s), 1e-8f);
    }
    __syncthreads();
    int ki = (bm[i >> 5] >> (i & 31)) & 1;   // block-uniform
    if (ki) {
        int nk = cnt;
        float ni = niS;
        const f32x4* xiv = (const f32x4*)xi;
        for (int u = t; u < nk; u += 256) {
            int j = kl[u];
            if (j == i) continue;
            const f32x4* ej = (const f32x4*)&emb[j * D_EMB];
            f32x4 er[16];
            f32x4 dv = {0.f, 0.f, 0.f, 0.f};
            f32x4 sv = {0.f, 0.f, 0.f, 0.f};
            #pragma unroll
            for (int d = 0; d < 16; ++d) {
                er[d] = ej[d];
                dv += xiv[d] * er[d];
                sv += er[d] * er[d];
            }
            float dot = dv[0] + dv[1] + dv[2] + dv[3];
            float nj = fmaxf(sqrtf(sv[0] + sv[1] + sv[2] + sv[3]), 1e-8f);
            if (dot > 0.5f * ni * nj) {
                atomicAdd(&degL, 1);
                #pragma unroll
                for (int d = 0; d < 16; ++d) {
                    atomicAdd(&aggL[d * 4 + 0], er[d][0]);
                    atomicAdd(&aggL[d * 4 + 1], er[d][1]);
                    atomicAdd(&aggL[d * 4 + 2], er[d][2]);
                    atomicAdd(&aggL[d * 4 + 3], er[d][3]);
                }
            }
        }
    }
    __syncthreads();
    if (t < D_EMB) {
        float deg = fmaxf((float)degL, 1.0f);
        aggL[t] = ki ? (aggL[t] / deg) : 0.f;    // aggL now holds aggd row
    }
    __syncthreads();
    if (t < P_DIM) {   // wave 0
        float s = lin_l_b[t];
        const float* wl = &lin_l_w[t * D_EMB];
        const float* wr = &lin_r_w[t * D_EMB];
        #pragma unroll
        for (int d = 0; d < D_EMB; ++d) s += aggL[d] * wl[d] + xi[d] * wr[d];
        pref[i * P_DIM + t] = s;
        float a = s * edge_w[t];
        float b = s * edge_w[P_DIM + t];
        #pragma unroll
        for (int off = 16; off; off >>= 1) { a += __shfl_xor(a, off, 64); b += __shfl_xor(b, off, 64); }
        if (t == 0) { av[i] = a; bv[i] = b; }
    }
}

// ---------------- tile-centric pack: each block owns one contiguous (tile, kt) region ----------------
// grid = dim3(65, 48): blockIdx.x = kt; blockIdx.y < 16 -> B tile nt ; >= 16 -> A tile rt = y-16
// Bp[nt][kt][r(128)][c^(r&7)] ; Ap[rt(32)][kt][r(64)][c^(r&7)]
__global__ __launch_bounds__(256) void k_pack(const float* __restrict__ comb_w, const float* __restrict__ comb_b,
                                              const int* __restrict__ wk_p, const int* __restrict__ vh_p,
                                              const float* __restrict__ dist, const float* __restrict__ pref,
                                              const float* __restrict__ av, const float* __restrict__ bv,
                                              const float* __restrict__ edge_b,
                                              u16* __restrict__ Bp, u16* __restrict__ Ap,
                                              float* __restrict__ cvec, float* __restrict__ w3) {
    int kt = blockIdx.x;       // 0..64
    int ty = blockIdx.y;       // 0..47
    int t = threadIdx.x;
    if (ty < 16) {             // ---- B tile: 128 rows x 64 cols = 1024 chunks of 16B ----
        int nt = ty;
        u16* tb = Bp + ((size_t)nt * NKT + kt) * 8192;
        #pragma unroll
        for (int it = 0; it < 4; ++it) {
            int q = t + it * 256;
            int r = q >> 3, c = q & 7;
            int j = nt * 128 + r;
            int k0 = kt * 64 + c * 8;
            const float* cw = comb_w + (size_t)j * IN_LEN;
            bf16x8 v;
            if (k0 < 4096) {
                f32x4 f0, f1;
                __builtin_memcpy(&f0, cw + 32 + k0, 16);
                __builtin_memcpy(&f1, cw + 36 + k0, 16);
                #pragma unroll
                for (int e = 0; e < 4; ++e) { v[e] = (short)f2bf(f0[e]); v[4 + e] = (short)f2bf(f1[e]); }
            } else if (k0 < 4128) {
                f32x4 f0, f1;
                __builtin_memcpy(&f0, cw + (k0 - 4096), 16);
                __builtin_memcpy(&f1, cw + (k0 - 4092), 16);
                #pragma unroll
                for (int e = 0; e < 4; ++e) { v[e] = (short)f2bf(f0[e]); v[4 + e] = (short)f2bf(f1[e]); }
            } else {
                #pragma unroll
                for (int e = 0; e < 8; ++e) v[e] = 0;
            }
            *(bf16x8*)&tb[r * 64 + ((c ^ (r & 7)) * 8)] = v;
        }
        if (kt == 64 && t < 128) {   // cvec/w3 once per row, done by the pad-kt blocks
            int j = nt * 128 + t;
            const float* cw = comb_w + (size_t)j * IN_LEN;
            float wk = (float)wk_p[0], vh = (float)vh_p[0];
            cvec[j] = wk * cw[4128] + vh * cw[4129] + comb_b[j];
            w3[j] = cw[4130];
        }
    } else {                   // ---- A tile: 64 rows x 64 cols = 512 chunks of 16B ----
        int rt = ty - 16;
        u16* ta = Ap + ((size_t)rt * NKT + kt) * 4096;
        float eb = edge_b[0];
        #pragma unroll
        for (int it = 0; it < 2; ++it) {
            int q = t + it * 256;
            int r = q >> 3, c = q & 7;
            int row = rt * 64 + r;
            int k0 = kt * 64 + c * 8;
            bf16x8 v;
            if (k0 < 2048) {                 // es region: no global row traffic, computed from av+bv
                float ab = av[row] + eb;
                f32x4 f0 = *(const f32x4*)(bv + k0);
                f32x4 f1 = *(const f32x4*)(bv + k0 + 4);
                #pragma unroll
                for (int e = 0; e < 4; ++e) {
                    float s0 = ab + f0[e]; s0 = (s0 >= 0.f) ? s0 : 0.01f * s0;
                    float s1 = ab + f1[e]; s1 = (s1 >= 0.f) ? s1 : 0.01f * s1;
                    v[e] = (short)f2bf(s0); v[4 + e] = (short)f2bf(s1);
                }
            } else if (k0 < 4096) {
                const f32x4* dp = (const f32x4*)(dist + (size_t)row * 2048 + (k0 - 2048));
                f32x4 f0 = dp[0], f1 = dp[1];
                #pragma unroll
                for (int e = 0; e < 4; ++e) { v[e] = (short)f2bf(f0[e]); v[4 + e] = (short)f2bf(f1[e]); }
            } else if (k0 < 4128) {
                const f32x4* pp = (const f32x4*)(pref + (size_t)row * P_DIM + (k0 - 4096));
                f32x4 f0 = pp[0], f1 = pp[1];
                #pragma unroll
                for (int e = 0; e < 4; ++e) { v[e] = (short)f2bf(f0[e]); v[4 + e] = (short)f2bf(f1[e]); }
            } else {
                #pragma unroll
                for (int e = 0; e < 8; ++e) v[e] = 0;
            }
            *(bf16x8*)&ta[r * 64 + ((c ^ (r & 7)) * 8)] = v;
        }
    }
}

// ---------------- 128x128-tile DMA GEMM: 4 waves of 64x64, dbuf, __syncthreads ----------------
// LDS-traffic-optimized: 45.7 LDS-B/kFLOP vs 68.6 for the 64x128 tile (reads scale with wave
// perimeter, FLOPs with area). 64 KB LDS -> 2 blocks/CU.
__global__ __launch_bounds__(256) void k_gemm_d(const u16* __restrict__ Ap, const u16* __restrict__ Bp,
                                                float* __restrict__ Cout) {
    __shared__ __attribute__((aligned(16))) short As[2][128 * 64];   // 2 x 16 KB
    __shared__ __attribute__((aligned(16))) short Bs[2][128 * 64];   // 2 x 16 KB
    int t = threadIdx.x;
    int mt = blockIdx.y, nt = blockIdx.x;
    int tileM = mt * 128, tileN = nt * 128;
    int lane = t & 63;
    int wid = t >> 6;
    int waveM = wid & 1, waveN = wid >> 1;
    int l16 = lane & 15, quad = lane >> 4;

    f32x4 acc[4][4];
    #pragma unroll
    for (int a_ = 0; a_ < 4; ++a_)
        #pragma unroll
        for (int b_ = 0; b_ < 4; ++b_) acc[a_][b_] = (f32x4){0.f, 0.f, 0.f, 0.f};

    const u16* gA = Ap + ((size_t)(2 * mt) * NKT) * 4096 + t * 8;   // strip 2*mt (rows 0..63)
    const size_t strideA = (size_t)NKT * 4096;                      // to strip 2*mt+1
    const u16* gB = Bp + ((size_t)nt * NKT) * 8192 + t * 8;

#define ISSUE(ktv, bb) do { \
        const u16* a0 = gA + (size_t)(ktv) * 4096; \
        const u16* a1 = a0 + strideA; \
        const u16* b0 = gB + (size_t)(ktv) * 8192; \
        u16* ad = (u16*)As[bb] + t * 8; \
        u16* bd = (u16*)Bs[bb] + t * 8; \
        gload16(a0, ad); \
        gload16(a0 + 2048, ad + 2048); \
        gload16(a1, ad + 4096); \
        gload16(a1 + 2048, ad + 6144); \
        gload16(b0, bd); \
        gload16(b0 + 2048, bd + 2048); \
        gload16(b0 + 4096, bd + 4096); \
        gload16(b0 + 6144, bd + 6144); \
    } while (0)

    // preload kt=0 into buffer 0
    ISSUE(0, 0);

    int cur = 0;
    for (int kt = 0; kt < NKT; ++kt) {
        __syncthreads();   // drains this tile's DMA (issued a full MFMA phase ago, except kt=0)
        if (kt + 1 < NKT) ISSUE(kt + 1, cur ^ 1);
        const short* Asc = As[cur];
        const short* Bsc = Bs[cur];
        #pragma unroll
        for (int kk = 0; kk < 64; kk += 32) {
            int cbase = kk >> 3;
            bf16x8 af[4], bfr[4];
            #pragma unroll
            for (int mi = 0; mi < 4; ++mi) {
                int row = waveM * 64 + mi * 16 + l16;
                af[mi] = *(const bf16x8*)&Asc[SWZ(row, cbase + quad)];
            }
            #pragma unroll
            for (int ni = 0; ni < 4; ++ni) {
                int row = waveN * 64 + ni * 16 + l16;
                bfr[ni] = *(const bf16x8*)&Bsc[SWZ(row, cbase + quad)];
            }
            #pragma unroll
            for (int mi = 0; mi < 4; ++mi)
                #pragma unroll
                for (int ni = 0; ni < 4; ++ni)
                    acc[mi][ni] = __builtin_amdgcn_mfma_f32_16x16x32_bf16(af[mi], bfr[ni], acc[mi][ni], 0, 0, 0);
        }
        cur ^= 1;
    }
#undef ISSUE
    #pragma unroll
    for (int mi = 0; mi < 4; ++mi)
        #pragma unroll
        for (int ni = 0; ni < 4; ++ni) {
            int row = tileM + waveM * 64 + mi * 16 + quad * 4;
            int col = tileN + waveN * 64 + ni * 16 + l16;
            float* cp = Cout + (size_t)row * N_NODES + col;
            #pragma unroll
            for (int rr = 0; rr < 4; ++rr) cp[(size_t)rr * N_NODES] = acc[mi][ni][rr];
        }
}

// ---------------- epilogue: + cvec + keep_i*w3, log-softmax (f32x4, in place, inline keep) ----------------
__global__ __launch_bounds__(256) void k_epi(const float* __restrict__ cvec, const float* __restrict__ w3,
                                             const int* __restrict__ stops, float* __restrict__ out) {
    int i = blockIdx.x, t = threadIdx.x;
    __shared__ int bm[64];
    __shared__ float redmax[4], redsum[4];
    if (t < 64) bm[t] = 0;
    __syncthreads();
    {
        int s0 = stops[t], s1 = stops[t + 256];
        atomicOr(&bm[s0 >> 5], 1 << (s0 & 31));
        atomicOr(&bm[s1 >> 5], 1 << (s1 & 31));
    }
    __syncthreads();
    float ki = (float)((bm[i >> 5] >> (i & 31)) & 1);
    f32x4* orow = (f32x4*)(out + (size_t)i * N_NODES);
    const f32x4* cv = (const f32x4*)cvec;
    const f32x4* wv = (const f32x4*)w3;
    f32x4 v0 = orow[t] + cv[t] + ki * wv[t];
    f32x4 v1 = orow[t + 256] + cv[t + 256] + ki * wv[t + 256];
    float vmax = fmaxf(fmaxf(fmaxf(v0[0], v0[1]), fmaxf(v0[2], v0[3])),
                       fmaxf(fmaxf(v1[0], v1[1]), fmaxf(v1[2], v1[3])));
    #pragma unroll
    for (int off = 32; off; off >>= 1) vmax = fmaxf(vmax, __shfl_xor(vmax, off, 64));
    if ((t & 63) == 0) redmax[t >> 6] = vmax;
    __syncthreads();
    vmax = fmaxf(fmaxf(redmax[0], redmax[1]), fmaxf(redmax[2], redmax[3]));
    float se = 0.f;
    #pragma unroll
    for (int e = 0; e < 4; ++e) se += expf(v0[e] - vmax) + expf(v1[e] - vmax);
    #pragma unroll
    for (int off = 32; off; off >>= 1) se += __shfl_xor(se, off, 64);
    if ((t & 63) == 0) redsum[t >> 6] = se;
    __syncthreads();
    se = redsum[0] + redsum[1] + redsum[2] + redsum[3];
    float lz = vmax + logf(se);
    orow[t] = v0 - lz;
    orow[t + 256] = v1 - lz;
}

extern "C" void kernel_launch(void* const* d_in, const int* in_sizes, int n_in,
                              void* d_out, int out_size, void* d_ws, size_t ws_size,
                              hipStream_t stream) {
    const float* dist    = (const float*)d_in[0];
    const float* emb     = (const float*)d_in[1];
    const float* lin_l_w = (const float*)d_in[2];
    const float* lin_l_b = (const float*)d_in[3];
    const float* lin_r_w = (const float*)d_in[4];
    const float* edge_w  = (const float*)d_in[5];
    const float* edge_b  = (const float*)d_in[6];
    const float* comb_w  = (const float*)d_in[7];
    const float* comb_b  = (const float*)d_in[8];
    const int* stops     = (const int*)d_in[9];
    const int* wk        = (const int*)d_in[10];
    const int* vh        = (const int*)d_in[11];

    // ws layout: 34.37 MB
    char* ws = (char*)d_ws;
    float* pref  = (float*)(ws + 0);          // 262144
    float* av    = (float*)(ws + 262144);     // 8192
    float* bv    = (float*)(ws + 270336);     // 8192
    float* cvec  = (float*)(ws + 278528);     // 8192
    float* w3    = (float*)(ws + 286720);     // 8192
    u16*   Ap    = (u16*)(ws + 294912);       // 17039360 -> 17334272
    u16*   Bp    = (u16*)(ws + 17334272);     // 17039360 -> 34373632
    float* out   = (float*)d_out;             // f32 [2048,2048]

    hipLaunchKernelGGL(k_aggpref, dim3(2048),   dim3(256), 0, stream, emb, stops,
                       lin_l_w, lin_l_b, lin_r_w, edge_w, pref, av, bv);
    hipLaunchKernelGGL(k_pack,    dim3(65, 48), dim3(256), 0, stream, comb_w, comb_b, wk, vh,
                       dist, pref, av, bv, edge_b, Bp, Ap, cvec, w3);
    hipLaunchKernelGGL(k_gemm_d,  dim3(16, 16), dim3(256), 0, stream, Ap, Bp, out);
    hipLaunchKernelGGL(k_epi,     dim3(2048),   dim3(256), 0, stream, cvec, w3, stops, out);
}

// Round 4
// 198.676 us; speedup vs baseline: 1.1105x; 1.1105x over previous
//
#include <hip/hip_runtime.h>

typedef unsigned short u16;
typedef __attribute__((ext_vector_type(8))) short bf16x8;
typedef __attribute__((ext_vector_type(4))) float f32x4;

// round-to-nearest (ties away): 2 VALU ops
__device__ __forceinline__ u16 f2bf(float f) {
    return (u16)((__float_as_uint(f) + 0x8000u) >> 16);
}

#define N_NODES 2048
#define D_EMB 64
#define P_DIM 32
#define NS_STOPS 512
#define IN_LEN 4131   // 32 + 2048 + 2048 + 3
#define NKT 65        // K-tiles of 64 (2048 es + 2048 dist + 32 pref + 32 pad)

// 16B-chunk XOR swizzle within a tile row (8 chunks of 8 shorts)
#define SWZ(row, c) ((((row) * 8) + ((c) ^ ((row) & 7))) * 8)

__device__ __forceinline__ void gload16(const u16* g, u16* l) {
    __builtin_amdgcn_global_load_lds((const __attribute__((address_space(1))) void*)g,
                                     (__attribute__((address_space(3))) void*)l, 16, 0, 0);
}

// ---------------- fused: stops bitmap + cosine graph + mean agg + pref + a,b (self-contained) ----------------
__global__ __launch_bounds__(256) void k_aggpref(const float* __restrict__ emb, const int* __restrict__ stops,
                                                 const float* __restrict__ lin_l_w, const float* __restrict__ lin_l_b,
                                                 const float* __restrict__ lin_r_w, const float* __restrict__ edge_w,
                                                 float* __restrict__ pref, float* __restrict__ av, float* __restrict__ bv) {
    int i = blockIdx.x, t = threadIdx.x;
    __shared__ int bm[64];          // 2048-bit stop bitmap
    __shared__ int kl[NS_STOPS];
    __shared__ int cnt, degL;
    __shared__ float xi[D_EMB];     // raw emb row i
    __shared__ float aggL[D_EMB];
    __shared__ float niS;
    if (t < 64) bm[t] = 0;
    if (t == 0) { cnt = 0; degL = 0; }
    if (t < D_EMB) { xi[t] = emb[i * D_EMB + t]; aggL[t] = 0.f; }
    __syncthreads();
    {   // scatter stops into bitmap
        int s0 = stops[t], s1 = stops[t + 256];
        atomicOr(&bm[s0 >> 5], 1 << (s0 & 31));
        atomicOr(&bm[s1 >> 5], 1 << (s1 & 31));
    }
    __syncthreads();
    {   // compact set nodes into kl
        int w = bm[t >> 2];          // thread t covers bits (t&3)*8 .. +7 of word t>>2
        int base = (t >> 2) * 32 + (t & 3) * 8;
        #pragma unroll
        for (int e = 0; e < 8; ++e)
            if ((w >> ((t & 3) * 8 + e)) & 1) { int p = atomicAdd(&cnt, 1); kl[p] = base + e; }
    }
    // norm of row i (wave 0)
    if (t < 64) {
        float s = xi[t] * xi[t];
        #pragma unroll
        for (int off = 32; off; off >>= 1) s += __shfl_xor(s, off, 64);
        if (t == 0) niS = fmaxf(sqrtf(s), 1e-8f);
    }
    __syncthreads();
    int ki = (bm[i >> 5] >> (i & 31)) & 1;   // block-uniform
    if (ki) {
        int nk = cnt;
        float ni = niS;
        const f32x4* xiv = (const f32x4*)xi;
        for (int u = t; u < nk; u += 256) {
            int j = kl[u];
            if (j == i) continue;
            const f32x4* ej = (const f32x4*)&emb[j * D_EMB];
            f32x4 er[16];
            f32x4 dv = {0.f, 0.f, 0.f, 0.f};
            f32x4 sv = {0.f, 0.f, 0.f, 0.f};
            #pragma unroll
            for (int d = 0; d < 16; ++d) {
                er[d] = ej[d];
                dv += xiv[d] * er[d];
                sv += er[d] * er[d];
            }
            float dot = dv[0] + dv[1] + dv[2] + dv[3];
            float nj = fmaxf(sqrtf(sv[0] + sv[1] + sv[2] + sv[3]), 1e-8f);
            if (dot > 0.5f * ni * nj) {
                atomicAdd(&degL, 1);
                #pragma unroll
                for (int d = 0; d < 16; ++d) {
                    atomicAdd(&aggL[d * 4 + 0], er[d][0]);
                    atomicAdd(&aggL[d * 4 + 1], er[d][1]);
                    atomicAdd(&aggL[d * 4 + 2], er[d][2]);
                    atomicAdd(&aggL[d * 4 + 3], er[d][3]);
                }
            }
        }
    }
    __syncthreads();
    if (t < D_EMB) {
        float deg = fmaxf((float)degL, 1.0f);
        aggL[t] = ki ? (aggL[t] / deg) : 0.f;    // aggL now holds aggd row
    }
    __syncthreads();
    if (t < P_DIM) {   // wave 0
        float s = lin_l_b[t];
        const float* wl = &lin_l_w[t * D_EMB];
        const float* wr = &lin_r_w[t * D_EMB];
        #pragma unroll
        for (int d = 0; d < D_EMB; ++d) s += aggL[d] * wl[d] + xi[d] * wr[d];
        pref[i * P_DIM + t] = s;
        float a = s * edge_w[t];
        float b = s * edge_w[P_DIM + t];
        #pragma unroll
        for (int off = 16; off; off >>= 1) { a += __shfl_xor(a, off, 64); b += __shfl_xor(b, off, 64); }
        if (t == 0) { av[i] = a; bv[i] = b; }
    }
}

// ---------------- tile-centric pack: each block owns one contiguous (tile, kt) region ----------------
// grid = dim3(65, 48): blockIdx.x = kt; blockIdx.y < 16 -> B tile nt ; >= 16 -> A tile rt = y-16
// Bp[nt][kt][r(128)][c^(r&7)] ; Ap[rt(32)][kt][r(64)][c^(r&7)]
__global__ __launch_bounds__(256) void k_pack(const float* __restrict__ comb_w, const float* __restrict__ comb_b,
                                              const int* __restrict__ wk_p, const int* __restrict__ vh_p,
                                              const float* __restrict__ dist, const float* __restrict__ pref,
                                              const float* __restrict__ av, const float* __restrict__ bv,
                                              const float* __restrict__ edge_b,
                                              u16* __restrict__ Bp, u16* __restrict__ Ap,
                                              float* __restrict__ cvec, float* __restrict__ w3) {
    int kt = blockIdx.x;       // 0..64
    int ty = blockIdx.y;       // 0..47
    int t = threadIdx.x;
    if (ty < 16) {             // ---- B tile: 128 rows x 64 cols = 1024 chunks of 16B ----
        int nt = ty;
        u16* tb = Bp + ((size_t)nt * NKT + kt) * 8192;
        #pragma unroll
        for (int it = 0; it < 4; ++it) {
            int q = t + it * 256;
            int r = q >> 3, c = q & 7;
            int j = nt * 128 + r;
            int k0 = kt * 64 + c * 8;
            const float* cw = comb_w + (size_t)j * IN_LEN;
            bf16x8 v;
            if (k0 < 4096) {
                f32x4 f0, f1;
                __builtin_memcpy(&f0, cw + 32 + k0, 16);
                __builtin_memcpy(&f1, cw + 36 + k0, 16);
                #pragma unroll
                for (int e = 0; e < 4; ++e) { v[e] = (short)f2bf(f0[e]); v[4 + e] = (short)f2bf(f1[e]); }
            } else if (k0 < 4128) {
                f32x4 f0, f1;
                __builtin_memcpy(&f0, cw + (k0 - 4096), 16);
                __builtin_memcpy(&f1, cw + (k0 - 4092), 16);
                #pragma unroll
                for (int e = 0; e < 4; ++e) { v[e] = (short)f2bf(f0[e]); v[4 + e] = (short)f2bf(f1[e]); }
            } else {
                #pragma unroll
                for (int e = 0; e < 8; ++e) v[e] = 0;
            }
            *(bf16x8*)&tb[r * 64 + ((c ^ (r & 7)) * 8)] = v;
        }
        if (kt == 64 && t < 128) {   // cvec/w3 once per row, done by the pad-kt blocks
            int j = nt * 128 + t;
            const float* cw = comb_w + (size_t)j * IN_LEN;
            float wk = (float)wk_p[0], vh = (float)vh_p[0];
            cvec[j] = wk * cw[4128] + vh * cw[4129] + comb_b[j];
            w3[j] = cw[4130];
        }
    } else {                   // ---- A tile: 64 rows x 64 cols = 512 chunks of 16B ----
        int rt = ty - 16;
        u16* ta = Ap + ((size_t)rt * NKT + kt) * 4096;
        float eb = edge_b[0];
        #pragma unroll
        for (int it = 0; it < 2; ++it) {
            int q = t + it * 256;
            int r = q >> 3, c = q & 7;
            int row = rt * 64 + r;
            int k0 = kt * 64 + c * 8;
            bf16x8 v;
            if (k0 < 2048) {                 // es region: no global row traffic, computed from av+bv
                float ab = av[row] + eb;
                f32x4 f0 = *(const f32x4*)(bv + k0);
                f32x4 f1 = *(const f32x4*)(bv + k0 + 4);
                #pragma unroll
                for (int e = 0; e < 4; ++e) {
                    float s0 = ab + f0[e]; s0 = (s0 >= 0.f) ? s0 : 0.01f * s0;
                    float s1 = ab + f1[e]; s1 = (s1 >= 0.f) ? s1 : 0.01f * s1;
                    v[e] = (short)f2bf(s0); v[4 + e] = (short)f2bf(s1);
                }
            } else if (k0 < 4096) {
                const f32x4* dp = (const f32x4*)(dist + (size_t)row * 2048 + (k0 - 2048));
                f32x4 f0 = dp[0], f1 = dp[1];
                #pragma unroll
                for (int e = 0; e < 4; ++e) { v[e] = (short)f2bf(f0[e]); v[4 + e] = (short)f2bf(f1[e]); }
            } else if (k0 < 4128) {
                const f32x4* pp = (const f32x4*)(pref + (size_t)row * P_DIM + (k0 - 4096));
                f32x4 f0 = pp[0], f1 = pp[1];
                #pragma unroll
                for (int e = 0; e < 4; ++e) { v[e] = (short)f2bf(f0[e]); v[4 + e] = (short)f2bf(f1[e]); }
            } else {
                #pragma unroll
                for (int e = 0; e < 8; ++e) v[e] = 0;
            }
            *(bf16x8*)&ta[r * 64 + ((c ^ (r & 7)) * 8)] = v;
        }
    }
}

// ---------------- in-block split-K GEMM: 128x128 tile, 8 waves, 2 K-groups of 4 waves ----------------
// Group g (waves 4g..4g+3) processes kt range [33g, 33g + (33-g)) with its own dbuf pipeline.
// Each wave owns a 64x64 sub-tile (best perimeter/area -> 1.5x less ds_read than 32x64).
// 128 KB LDS -> 1 block/CU but 8 waves = 2/SIMD for latency hiding; each barrier phase
// carries 2 kt of MFMA (both groups) per drain. Final cross-group reduce via LDS.
__global__ __launch_bounds__(512) void k_gemm_d(const u16* __restrict__ Ap, const u16* __restrict__ Bp,
                                                float* __restrict__ Cout) {
    __shared__ __attribute__((aligned(16))) short As[2][2][8192];   // [group][buf][128r x 64c] 64 KB
    __shared__ __attribute__((aligned(16))) short Bs[2][2][8192];   // 64 KB
    int t = threadIdx.x;            // 0..511
    int mt = blockIdx.y, nt = blockIdx.x;
    int lane = t & 63;
    int wid = t >> 6;               // 0..7
    int g = wid >> 2;               // K-group
    int wq = wid & 3;               // wave within group
    int waveM = wq & 1, waveN = wq >> 1;
    int l16 = lane & 15, quad = lane >> 4;
    int tt = t & 255;               // staging index within group (t>>8 == g)

    f32x4 acc[4][4];
    #pragma unroll
    for (int a_ = 0; a_ < 4; ++a_)
        #pragma unroll
        for (int b_ = 0; b_ < 4; ++b_) acc[a_][b_] = (f32x4){0.f, 0.f, 0.f, 0.f};

#define ISSUE(ktv, bb) do { \
        const u16* a0 = Ap + ((size_t)(2 * mt) * NKT + (ktv)) * 4096 + tt * 8; \
        const u16* a1 = a0 + (size_t)NKT * 4096; \
        const u16* b0 = Bp + ((size_t)nt * NKT + (ktv)) * 8192 + tt * 8; \
        u16* ad = (u16*)As[g][bb] + tt * 8; \
        u16* bd = (u16*)Bs[g][bb] + tt * 8; \
        gload16(a0, ad); \
        gload16(a0 + 2048, ad + 2048); \
        gload16(a1, ad + 4096); \
        gload16(a1 + 2048, ad + 6144); \
        gload16(b0, bd); \
        gload16(b0 + 2048, bd + 2048); \
        gload16(b0 + 4096, bd + 4096); \
        gload16(b0 + 6144, bd + 6144); \
    } while (0)

    const int kt0 = g ? 33 : 0;
    const int nkt = g ? 32 : 33;    // group0: kt 0..32, group1: kt 33..64

    ISSUE(kt0, 0);                  // each group preloads its first tile

    int cur = 0;
    for (int p = 0; p < 33; ++p) {
        __syncthreads();            // drains both groups' DMA for buf cur
        if (p + 1 < nkt) ISSUE(kt0 + p + 1, cur ^ 1);
        if (p < nkt) {
            const short* Asc = As[g][cur];
            const short* Bsc = Bs[g][cur];
            #pragma unroll
            for (int kk = 0; kk < 64; kk += 32) {
                int cbase = kk >> 3;
                bf16x8 af[4], bfr[4];
                #pragma unroll
                for (int mi = 0; mi < 4; ++mi) {
                    int row = waveM * 64 + mi * 16 + l16;
                    af[mi] = *(const bf16x8*)&Asc[SWZ(row, cbase + quad)];
                }
                #pragma unroll
                for (int ni = 0; ni < 4; ++ni) {
                    int row = waveN * 64 + ni * 16 + l16;
                    bfr[ni] = *(const bf16x8*)&Bsc[SWZ(row, cbase + quad)];
                }
                #pragma unroll
                for (int mi = 0; mi < 4; ++mi)
                    #pragma unroll
                    for (int ni = 0; ni < 4; ++ni)
                        acc[mi][ni] = __builtin_amdgcn_mfma_f32_16x16x32_bf16(af[mi], bfr[ni], acc[mi][ni], 0, 0, 0);
            }
        }
        cur ^= 1;
    }
#undef ISSUE

    // ---- cross-group reduction: group1 partials -> LDS (XOR-swizzled), group0 adds & stores ----
    __syncthreads();                          // all compute done; staging LDS reusable
    float* red = (float*)&As[0][0][0];        // 64 KB = 4 waves x 16 KB
    if (g == 1) {
        float* wb = red + wq * 4096;          // this wave's 16 KB region
        #pragma unroll
        for (int mi = 0; mi < 4; ++mi)
            #pragma unroll
            for (int ni = 0; ni < 4; ++ni) {
                int i = mi * 4 + ni;
                int unit = lane * 16 + (i ^ (lane & 15));   // conflict-spread, bijective per lane
                *(f32x4*)(wb + unit * 4) = acc[mi][ni];
            }
    }
    __syncthreads();
    if (g == 0) {
        float* wb = red + wq * 4096;
        #pragma unroll
        for (int mi = 0; mi < 4; ++mi)
            #pragma unroll
            for (int ni = 0; ni < 4; ++ni) {
                int i = mi * 4 + ni;
                int unit = lane * 16 + (i ^ (lane & 15));
                acc[mi][ni] += *(const f32x4*)(wb + unit * 4);
                int row = mt * 128 + waveM * 64 + mi * 16 + quad * 4;
                int col = nt * 128 + waveN * 64 + ni * 16 + l16;
                float* cp = Cout + (size_t)row * N_NODES + col;
                #pragma unroll
                for (int rr = 0; rr < 4; ++rr) cp[(size_t)rr * N_NODES] = acc[mi][ni][rr];
            }
    }
}

// ---------------- epilogue: + cvec + keep_i*w3, log-softmax (f32x4, in place, inline keep) ----------------
__global__ __launch_bounds__(256) void k_epi(const float* __restrict__ cvec, const float* __restrict__ w3,
                                             const int* __restrict__ stops, float* __restrict__ out) {
    int i = blockIdx.x, t = threadIdx.x;
    __shared__ int bm[64];
    __shared__ float redmax[4], redsum[4];
    if (t < 64) bm[t] = 0;
    __syncthreads();
    {
        int s0 = stops[t], s1 = stops[t + 256];
        atomicOr(&bm[s0 >> 5], 1 << (s0 & 31));
        atomicOr(&bm[s1 >> 5], 1 << (s1 & 31));
    }
    __syncthreads();
    float ki = (float)((bm[i >> 5] >> (i & 31)) & 1);
    f32x4* orow = (f32x4*)(out + (size_t)i * N_NODES);
    const f32x4* cv = (const f32x4*)cvec;
    const f32x4* wv = (const f32x4*)w3;
    f32x4 v0 = orow[t] + cv[t] + ki * wv[t];
    f32x4 v1 = orow[t + 256] + cv[t + 256] + ki * wv[t + 256];
    float vmax = fmaxf(fmaxf(fmaxf(v0[0], v0[1]), fmaxf(v0[2], v0[3])),
                       fmaxf(fmaxf(v1[0], v1[1]), fmaxf(v1[2], v1[3])));
    #pragma unroll
    for (int off = 32; off; off >>= 1) vmax = fmaxf(vmax, __shfl_xor(vmax, off, 64));
    if ((t & 63) == 0) redmax[t >> 6] = vmax;
    __syncthreads();
    vmax = fmaxf(fmaxf(redmax[0], redmax[1]), fmaxf(redmax[2], redmax[3]));
    float se = 0.f;
    #pragma unroll
    for (int e = 0; e < 4; ++e) se += expf(v0[e] - vmax) + expf(v1[e] - vmax);
    #pragma unroll
    for (int off = 32; off; off >>= 1) se += __shfl_xor(se, off, 64);
    if ((t & 63) == 0) redsum[t >> 6] = se;
    __syncthreads();
    se = redsum[0] + redsum[1] + redsum[2] + redsum[3];
    float lz = vmax + logf(se);
    orow[t] = v0 - lz;
    orow[t + 256] = v1 - lz;
}

extern "C" void kernel_launch(void* const* d_in, const int* in_sizes, int n_in,
                              void* d_out, int out_size, void* d_ws, size_t ws_size,
                              hipStream_t stream) {
    const float* dist    = (const float*)d_in[0];
    const float* emb     = (const float*)d_in[1];
    const float* lin_l_w = (const float*)d_in[2];
    const float* lin_l_b = (const float*)d_in[3];
    const float* lin_r_w = (const float*)d_in[4];
    const float* edge_w  = (const float*)d_in[5];
    const float* edge_b  = (const float*)d_in[6];
    const float* comb_w  = (const float*)d_in[7];
    const float* comb_b  = (const float*)d_in[8];
    const int* stops     = (const int*)d_in[9];
    const int* wk        = (const int*)d_in[10];
    const int* vh        = (const int*)d_in[11];

    // ws layout: 34.37 MB
    char* ws = (char*)d_ws;
    float* pref  = (float*)(ws + 0);          // 262144
    float* av    = (float*)(ws + 262144);     // 8192
    float* bv    = (float*)(ws + 270336);     // 8192
    float* cvec  = (float*)(ws + 278528);     // 8192
    float* w3    = (float*)(ws + 286720);     // 8192
    u16*   Ap    = (u16*)(ws + 294912);       // 17039360 -> 17334272
    u16*   Bp    = (u16*)(ws + 17334272);     // 17039360 -> 34373632
    float* out   = (float*)d_out;             // f32 [2048,2048]

    hipLaunchKernelGGL(k_aggpref, dim3(2048),   dim3(256), 0, stream, emb, stops,
                       lin_l_w, lin_l_b, lin_r_w, edge_w, pref, av, bv);
    hipLaunchKernelGGL(k_pack,    dim3(65, 48), dim3(256), 0, stream, comb_w, comb_b, wk, vh,
                       dist, pref, av, bv, edge_b, Bp, Ap, cvec, w3);
    hipLaunchKernelGGL(k_gemm_d,  dim3(16, 16), dim3(512), 0, stream, Ap, Bp, out);
    hipLaunchKernelGGL(k_epi,     dim3(2048),   dim3(256), 0, stream, cvec, w3, stops, out);
}

// Round 5
// 192.351 us; speedup vs baseline: 1.1471x; 1.0329x over previous
//
#include <hip/hip_runtime.h>

typedef unsigned short u16;
typedef __attribute__((ext_vector_type(8))) short bf16x8;
typedef __attribute__((ext_vector_type(4))) float f32x4;

// round-to-nearest (ties away): 2 VALU ops
__device__ __forceinline__ u16 f2bf(float f) {
    return (u16)((__float_as_uint(f) + 0x8000u) >> 16);
}

#define N_NODES 2048
#define D_EMB 64
#define P_DIM 32
#define NS_STOPS 512
#define IN_LEN 4131   // 32 + 2048 + 2048 + 3
#define NKT 65        // K-tiles of 64 (2048 es + 2048 dist + 32 pref + 32 pad)

// 16B-chunk XOR swizzle within a tile row (8 chunks of 8 shorts)
#define SWZ(row, c) ((((row) * 8) + ((c) ^ ((row) & 7))) * 8)

__device__ __forceinline__ void gload16(const u16* g, u16* l) {
    __builtin_amdgcn_global_load_lds((const __attribute__((address_space(1))) void*)g,
                                     (__attribute__((address_space(3))) void*)l, 16, 0, 0);
}

// ---------------- fused: stops bitmap + cosine graph + mean agg + pref + a,b (self-contained) ----------------
__global__ __launch_bounds__(256) void k_aggpref(const float* __restrict__ emb, const int* __restrict__ stops,
                                                 const float* __restrict__ lin_l_w, const float* __restrict__ lin_l_b,
                                                 const float* __restrict__ lin_r_w, const float* __restrict__ edge_w,
                                                 float* __restrict__ pref, float* __restrict__ av, float* __restrict__ bv) {
    int i = blockIdx.x, t = threadIdx.x;
    __shared__ int bm[64];          // 2048-bit stop bitmap
    __shared__ int kl[NS_STOPS];
    __shared__ int cnt, degL;
    __shared__ float xi[D_EMB];     // raw emb row i
    __shared__ float aggL[D_EMB];
    __shared__ float niS;
    if (t < 64) bm[t] = 0;
    if (t == 0) { cnt = 0; degL = 0; }
    if (t < D_EMB) { xi[t] = emb[i * D_EMB + t]; aggL[t] = 0.f; }
    __syncthreads();
    {   // scatter stops into bitmap
        int s0 = stops[t], s1 = stops[t + 256];
        atomicOr(&bm[s0 >> 5], 1 << (s0 & 31));
        atomicOr(&bm[s1 >> 5], 1 << (s1 & 31));
    }
    __syncthreads();
    {   // compact set nodes into kl
        int w = bm[t >> 2];          // thread t covers bits (t&3)*8 .. +7 of word t>>2
        int base = (t >> 2) * 32 + (t & 3) * 8;
        #pragma unroll
        for (int e = 0; e < 8; ++e)
            if ((w >> ((t & 3) * 8 + e)) & 1) { int p = atomicAdd(&cnt, 1); kl[p] = base + e; }
    }
    // norm of row i (wave 0)
    if (t < 64) {
        float s = xi[t] * xi[t];
        #pragma unroll
        for (int off = 32; off; off >>= 1) s += __shfl_xor(s, off, 64);
        if (t == 0) niS = fmaxf(sqrtf(s), 1e-8f);
    }
    __syncthreads();
    int ki = (bm[i >> 5] >> (i & 31)) & 1;   // block-uniform
    if (ki) {
        int nk = cnt;
        float ni = niS;
        const f32x4* xiv = (const f32x4*)xi;
        for (int u = t; u < nk; u += 256) {
            int j = kl[u];
            if (j == i) continue;
            const f32x4* ej = (const f32x4*)&emb[j * D_EMB];
            f32x4 er[16];
            f32x4 dv = {0.f, 0.f, 0.f, 0.f};
            f32x4 sv = {0.f, 0.f, 0.f, 0.f};
            #pragma unroll
            for (int d = 0; d < 16; ++d) {
                er[d] = ej[d];
                dv += xiv[d] * er[d];
                sv += er[d] * er[d];
            }
            float dot = dv[0] + dv[1] + dv[2] + dv[3];
            float nj = fmaxf(sqrtf(sv[0] + sv[1] + sv[2] + sv[3]), 1e-8f);
            if (dot > 0.5f * ni * nj) {
                atomicAdd(&degL, 1);
                #pragma unroll
                for (int d = 0; d < 16; ++d) {
                    atomicAdd(&aggL[d * 4 + 0], er[d][0]);
                    atomicAdd(&aggL[d * 4 + 1], er[d][1]);
                    atomicAdd(&aggL[d * 4 + 2], er[d][2]);
                    atomicAdd(&aggL[d * 4 + 3], er[d][3]);
                }
            }
        }
    }
    __syncthreads();
    if (t < D_EMB) {
        float deg = fmaxf((float)degL, 1.0f);
        aggL[t] = ki ? (aggL[t] / deg) : 0.f;    // aggL now holds aggd row
    }
    __syncthreads();
    if (t < P_DIM) {   // wave 0
        float s = lin_l_b[t];
        const float* wl = &lin_l_w[t * D_EMB];
        const float* wr = &lin_r_w[t * D_EMB];
        #pragma unroll
        for (int d = 0; d < D_EMB; ++d) s += aggL[d] * wl[d] + xi[d] * wr[d];
        pref[i * P_DIM + t] = s;
        float a = s * edge_w[t];
        float b = s * edge_w[P_DIM + t];
        #pragma unroll
        for (int off = 16; off; off >>= 1) { a += __shfl_xor(a, off, 64); b += __shfl_xor(b, off, 64); }
        if (t == 0) { av[i] = a; bv[i] = b; }
    }
}

// ---------------- tile-centric pack: each block owns one contiguous (tile, kt) region ----------------
// grid = dim3(65, 48): blockIdx.x = kt; blockIdx.y < 16 -> B tile nt ; >= 16 -> A tile rt = y-16
// Bp[nt][kt][r(128)][c^(r&7)] ; Ap[rt(32)][kt][r(64)][c^(r&7)]
__global__ __launch_bounds__(256) void k_pack(const float* __restrict__ comb_w, const float* __restrict__ comb_b,
                                              const int* __restrict__ wk_p, const int* __restrict__ vh_p,
                                              const float* __restrict__ dist, const float* __restrict__ pref,
                                              const float* __restrict__ av, const float* __restrict__ bv,
                                              const float* __restrict__ edge_b,
                                              u16* __restrict__ Bp, u16* __restrict__ Ap,
                                              float* __restrict__ cvec, float* __restrict__ w3) {
    int kt = blockIdx.x;       // 0..64
    int ty = blockIdx.y;       // 0..47
    int t = threadIdx.x;
    if (ty < 16) {             // ---- B tile: 128 rows x 64 cols = 1024 chunks of 16B ----
        int nt = ty;
        u16* tb = Bp + ((size_t)nt * NKT + kt) * 8192;
        #pragma unroll
        for (int it = 0; it < 4; ++it) {
            int q = t + it * 256;
            int r = q >> 3, c = q & 7;
            int j = nt * 128 + r;
            int k0 = kt * 64 + c * 8;
            const float* cw = comb_w + (size_t)j * IN_LEN;
            bf16x8 v;
            if (k0 < 4096) {
                f32x4 f0, f1;
                __builtin_memcpy(&f0, cw + 32 + k0, 16);
                __builtin_memcpy(&f1, cw + 36 + k0, 16);
                #pragma unroll
                for (int e = 0; e < 4; ++e) { v[e] = (short)f2bf(f0[e]); v[4 + e] = (short)f2bf(f1[e]); }
            } else if (k0 < 4128) {
                f32x4 f0, f1;
                __builtin_memcpy(&f0, cw + (k0 - 4096), 16);
                __builtin_memcpy(&f1, cw + (k0 - 4092), 16);
                #pragma unroll
                for (int e = 0; e < 4; ++e) { v[e] = (short)f2bf(f0[e]); v[4 + e] = (short)f2bf(f1[e]); }
            } else {
                #pragma unroll
                for (int e = 0; e < 8; ++e) v[e] = 0;
            }
            *(bf16x8*)&tb[r * 64 + ((c ^ (r & 7)) * 8)] = v;
        }
        if (kt == 64 && t < 128) {   // cvec/w3 once per row, done by the pad-kt blocks
            int j = nt * 128 + t;
            const float* cw = comb_w + (size_t)j * IN_LEN;
            float wk = (float)wk_p[0], vh = (float)vh_p[0];
            cvec[j] = wk * cw[4128] + vh * cw[4129] + comb_b[j];
            w3[j] = cw[4130];
        }
    } else {                   // ---- A tile: 64 rows x 64 cols = 512 chunks of 16B ----
        int rt = ty - 16;
        u16* ta = Ap + ((size_t)rt * NKT + kt) * 4096;
        float eb = edge_b[0];
        #pragma unroll
        for (int it = 0; it < 2; ++it) {
            int q = t + it * 256;
            int r = q >> 3, c = q & 7;
            int row = rt * 64 + r;
            int k0 = kt * 64 + c * 8;
            bf16x8 v;
            if (k0 < 2048) {                 // es region: no global row traffic, computed from av+bv
                float ab = av[row] + eb;
                f32x4 f0 = *(const f32x4*)(bv + k0);
                f32x4 f1 = *(const f32x4*)(bv + k0 + 4);
                #pragma unroll
                for (int e = 0; e < 4; ++e) {
                    float s0 = ab + f0[e]; s0 = (s0 >= 0.f) ? s0 : 0.01f * s0;
                    float s1 = ab + f1[e]; s1 = (s1 >= 0.f) ? s1 : 0.01f * s1;
                    v[e] = (short)f2bf(s0); v[4 + e] = (short)f2bf(s1);
                }
            } else if (k0 < 4096) {
                const f32x4* dp = (const f32x4*)(dist + (size_t)row * 2048 + (k0 - 2048));
                f32x4 f0 = dp[0], f1 = dp[1];
                #pragma unroll
                for (int e = 0; e < 4; ++e) { v[e] = (short)f2bf(f0[e]); v[4 + e] = (short)f2bf(f1[e]); }
            } else if (k0 < 4128) {
                const f32x4* pp = (const f32x4*)(pref + (size_t)row * P_DIM + (k0 - 4096));
                f32x4 f0 = pp[0], f1 = pp[1];
                #pragma unroll
                for (int e = 0; e < 4; ++e) { v[e] = (short)f2bf(f0[e]); v[4 + e] = (short)f2bf(f1[e]); }
            } else {
                #pragma unroll
                for (int e = 0; e < 8; ++e) v[e] = 0;
            }
            *(bf16x8*)&ta[r * 64 + ((c ^ (r & 7)) * 8)] = v;
        }
    }
}

// ---------------- 64x64-tile DMA GEMM: 4 blocks/CU TLP + XCD-chunked swizzle ----------------
// 1024 blocks (4/CU) at independent pipeline phases hide each other's barrier/DMA stalls
// (m114 mechanism; m97's 874-TF regime was ~3 blocks/CU of this same 2-phase loop).
// XCD swizzle: each XCD's 128 blocks = contiguous 16mt x 8nt chunk -> per-kt hot slice
// (24 strips x 8 KB = 192 KB) L2-resident; L3 re-read traffic ~1.1 GB -> ~40 MB (T1).
// LDS 32 KB/block (4 x 32 = 128 <= 160), __launch_bounds__(256,4) caps VGPR for 16 waves/CU.
__global__ __launch_bounds__(256, 4) void k_gemm_d(const u16* __restrict__ Ap, const u16* __restrict__ Bp,
                                                   float* __restrict__ Cout) {
    __shared__ __attribute__((aligned(16))) short As[2][4096];   // 2 x 8 KB
    __shared__ __attribute__((aligned(16))) short Bs[2][4096];   // 2 x 8 KB
    int t = threadIdx.x;
    // bijective XCD-chunk decode: xcd = bid&7 (round-robin), chunk = 16mt x 8nt
    int b = blockIdx.x;                 // 0..1023
    int c = b & 7, u = b >> 3;          // chunk id, index within chunk
    int mt = (c & 1) * 16 + (u & 15);   // 0..31
    int nt = (c >> 1) * 8 + (u >> 4);   // 0..31
    int tileM = mt * 64, tileN = nt * 64;
    int lane = t & 63;
    int wid = t >> 6;                   // 0..3
    int waveM = wid & 1, waveN = wid >> 1;
    int l16 = lane & 15, quad = lane >> 4;

    f32x4 acc[2][2];
    #pragma unroll
    for (int a_ = 0; a_ < 2; ++a_)
        #pragma unroll
        for (int b_ = 0; b_ < 2; ++b_) acc[a_][b_] = (f32x4){0.f, 0.f, 0.f, 0.f};

    // A: strip mt (64 rows), 4096 u16 per kt.  B: 64-row half of 128-row strip nt>>1.
    const u16* gA = Ap + ((size_t)mt * NKT) * 4096 + t * 8;
    const u16* gB = Bp + ((size_t)(nt >> 1) * NKT) * 8192 + (nt & 1) * 4096 + t * 8;

#define ISSUE(ktv, bb) do { \
        const u16* a0 = gA + (size_t)(ktv) * 4096; \
        const u16* b0 = gB + (size_t)(ktv) * 8192; \
        u16* ad = (u16*)As[bb] + t * 8; \
        u16* bd = (u16*)Bs[bb] + t * 8; \
        gload16(a0, ad); \
        gload16(a0 + 2048, ad + 2048); \
        gload16(b0, bd); \
        gload16(b0 + 2048, bd + 2048); \
    } while (0)

    ISSUE(0, 0);   // preload kt=0 into buffer 0

    int cur = 0;
    for (int kt = 0; kt < NKT; ++kt) {
        __syncthreads();   // drains this tile's DMA (issued a full MFMA phase ago, except kt=0)
        if (kt + 1 < NKT) ISSUE(kt + 1, cur ^ 1);
        const short* Asc = As[cur];
        const short* Bsc = Bs[cur];
        #pragma unroll
        for (int kk = 0; kk < 64; kk += 32) {
            int cbase = kk >> 3;
            bf16x8 af[2], bfr[2];
            #pragma unroll
            for (int mi = 0; mi < 2; ++mi) {
                int row = waveM * 32 + mi * 16 + l16;
                af[mi] = *(const bf16x8*)&Asc[SWZ(row, cbase + quad)];
            }
            #pragma unroll
            for (int ni = 0; ni < 2; ++ni) {
                int row = waveN * 32 + ni * 16 + l16;
                bfr[ni] = *(const bf16x8*)&Bsc[SWZ(row, cbase + quad)];
            }
            #pragma unroll
            for (int mi = 0; mi < 2; ++mi)
                #pragma unroll
                for (int ni = 0; ni < 2; ++ni)
                    acc[mi][ni] = __builtin_amdgcn_mfma_f32_16x16x32_bf16(af[mi], bfr[ni], acc[mi][ni], 0, 0, 0);
        }
        cur ^= 1;
    }
#undef ISSUE
    #pragma unroll
    for (int mi = 0; mi < 2; ++mi)
        #pragma unroll
        for (int ni = 0; ni < 2; ++ni) {
            int row = tileM + waveM * 32 + mi * 16 + quad * 4;
            int col = tileN + waveN * 32 + ni * 16 + l16;
            float* cp = Cout + (size_t)row * N_NODES + col;
            #pragma unroll
            for (int rr = 0; rr < 4; ++rr) cp[(size_t)rr * N_NODES] = acc[mi][ni][rr];
        }
}

// ---------------- epilogue: + cvec + keep_i*w3, log-softmax (f32x4, in place, inline keep) ----------------
__global__ __launch_bounds__(256) void k_epi(const float* __restrict__ cvec, const float* __restrict__ w3,
                                             const int* __restrict__ stops, float* __restrict__ out) {
    int i = blockIdx.x, t = threadIdx.x;
    __shared__ int bm[64];
    __shared__ float redmax[4], redsum[4];
    if (t < 64) bm[t] = 0;
    __syncthreads();
    {
        int s0 = stops[t], s1 = stops[t + 256];
        atomicOr(&bm[s0 >> 5], 1 << (s0 & 31));
        atomicOr(&bm[s1 >> 5], 1 << (s1 & 31));
    }
    __syncthreads();
    float ki = (float)((bm[i >> 5] >> (i & 31)) & 1);
    f32x4* orow = (f32x4*)(out + (size_t)i * N_NODES);
    const f32x4* cv = (const f32x4*)cvec;
    const f32x4* wv = (const f32x4*)w3;
    f32x4 v0 = orow[t] + cv[t] + ki * wv[t];
    f32x4 v1 = orow[t + 256] + cv[t + 256] + ki * wv[t + 256];
    float vmax = fmaxf(fmaxf(fmaxf(v0[0], v0[1]), fmaxf(v0[2], v0[3])),
                       fmaxf(fmaxf(v1[0], v1[1]), fmaxf(v1[2], v1[3])));
    #pragma unroll
    for (int off = 32; off; off >>= 1) vmax = fmaxf(vmax, __shfl_xor(vmax, off, 64));
    if ((t & 63) == 0) redmax[t >> 6] = vmax;
    __syncthreads();
    vmax = fmaxf(fmaxf(redmax[0], redmax[1]), fmaxf(redmax[2], redmax[3]));
    float se = 0.f;
    #pragma unroll
    for (int e = 0; e < 4; ++e) se += expf(v0[e] - vmax) + expf(v1[e] - vmax);
    #pragma unroll
    for (int off = 32; off; off >>= 1) se += __shfl_xor(se, off, 64);
    if ((t & 63) == 0) redsum[t >> 6] = se;
    __syncthreads();
    se = redsum[0] + redsum[1] + redsum[2] + redsum[3];
    float lz = vmax + logf(se);
    orow[t] = v0 - lz;
    orow[t + 256] = v1 - lz;
}

extern "C" void kernel_launch(void* const* d_in, const int* in_sizes, int n_in,
                              void* d_out, int out_size, void* d_ws, size_t ws_size,
                              hipStream_t stream) {
    const float* dist    = (const float*)d_in[0];
    const float* emb     = (const float*)d_in[1];
    const float* lin_l_w = (const float*)d_in[2];
    const float* lin_l_b = (const float*)d_in[3];
    const float* lin_r_w = (const float*)d_in[4];
    const float* edge_w  = (const float*)d_in[5];
    const float* edge_b  = (const float*)d_in[6];
    const float* comb_w  = (const float*)d_in[7];
    const float* comb_b  = (const float*)d_in[8];
    const int* stops     = (const int*)d_in[9];
    const int* wk        = (const int*)d_in[10];
    const int* vh        = (const int*)d_in[11];

    // ws layout: 34.37 MB
    char* ws = (char*)d_ws;
    float* pref  = (float*)(ws + 0);          // 262144
    float* av    = (float*)(ws + 262144);     // 8192
    float* bv    = (float*)(ws + 270336);     // 8192
    float* cvec  = (float*)(ws + 278528);     // 8192
    float* w3    = (float*)(ws + 286720);     // 8192
    u16*   Ap    = (u16*)(ws + 294912);       // 17039360 -> 17334272
    u16*   Bp    = (u16*)(ws + 17334272);     // 17039360 -> 34373632
    float* out   = (float*)d_out;             // f32 [2048,2048]

    hipLaunchKernelGGL(k_aggpref, dim3(2048),   dim3(256), 0, stream, emb, stops,
                       lin_l_w, lin_l_b, lin_r_w, edge_w, pref, av, bv);
    hipLaunchKernelGGL(k_pack,    dim3(65, 48), dim3(256), 0, stream, comb_w, comb_b, wk, vh,
                       dist, pref, av, bv, edge_b, Bp, Ap, cvec, w3);
    hipLaunchKernelGGL(k_gemm_d,  dim3(1024),   dim3(256), 0, stream, Ap, Bp, out);
    hipLaunchKernelGGL(k_epi,     dim3(2048),   dim3(256), 0, stream, cvec, w3, stops, out);
}